// Round 6
// baseline (192.273 us; speedup 1.0000x reference)
//
#include <hip/hip_runtime.h>
#include <stdint.h>

#define BATCH 4096

typedef float v16f __attribute__((ext_vector_type(16)));
typedef short v8s  __attribute__((ext_vector_type(8)));

// ---------------------------------------------------------------------------
// conv0f: the ONLY conv0 pass. conv + pool (canonical FMA order, bit-identical
// to prior sessions) + batch stats + FOLDED signw + store of pooled pre-BN m:
//   m [n][196][32] fp32 (102.8 MB).
// Downstream consumers rebuild everything from m:
//   conv1s: sign image = sign(fmaf(sc0,m,sh0)) built into LDS directly.
//   bc2m:   hp0 = fmaf(sc0, sc0>0 ? max4(m) : min4(m), sh0) -- bit-identical
//           because correctly-rounded fma is monotone in its multiplicand for
//           fixed sc sign (and sc==0 gives sh0 either way).
// FROZEN: the conv FMA order AND the stats accumulation order (rs[c*14+py]
// then t<32 serial sum). Remapping threads would change part0 in the last
// ulp -> BN coeff ulp shifts -> sign flips in binary convs -> FAIL.
// ---------------------------------------------------------------------------
__global__ __launch_bounds__(448) void k_conv0f(const float* __restrict__ x,
                                                const float* __restrict__ w0,
                                                const float* __restrict__ w1,
                                                const float* __restrict__ w2,
                                                uint16_t* __restrict__ w1f,
                                                uint16_t* __restrict__ w2f,
                                                double* __restrict__ part0,
                                                float* __restrict__ mg) {
    __shared__ float xs[960];   // 30 rows x 32 cols (zero halo)
    __shared__ float wl[288];
    __shared__ double rs[448], rq[448];   // [c*14+py]
    int n = blockIdx.x, t = threadIdx.x;

    if (n < 72 && t < 256) {
        int i = n * 256 + t;
        int ii = (i < 9216) ? i : i - 9216;
        const float* w = (i < 9216) ? w1 : w2;
        uint16_t* o = (i < 9216) ? w1f : w2f;
        int j = ii & 7, nn = (ii >> 3) & 31, q2 = (ii >> 8) & 1, kh = (ii >> 9) & 1, tp = ii >> 10;
        int cin = kh * 16 + q2 * 8 + j;
        float v = w[(nn * 32 + cin) * 9 + tp];
        o[ii] = (v > 0.f) ? 0x3F80 : ((v < 0.f) ? 0xBF80 : 0);
    }

    for (int i = t; i < 960; i += 448) xs[i] = 0.f;
    for (int i = t; i < 288; i += 448) wl[i] = w0[i];
    __syncthreads();
    for (int i = t; i < 784; i += 448) {
        int y = i / 28, xx = i - y * 28;
        xs[(y + 1) * 32 + xx + 1] = x[n * 784 + i];
    }
    __syncthreads();
    int c = t & 31, py = t >> 5;
    float wreg[9];
    #pragma unroll
    for (int i = 0; i < 9; ++i) wreg[i] = wl[c * 9 + i];
    const float4* X4 = (const float4*)xs;
    float4 cur0 = X4[(2 * py + 0) * 8];
    float4 cur1 = X4[(2 * py + 1) * 8];
    float4 cur2 = X4[(2 * py + 2) * 8];
    float4 cur3 = X4[(2 * py + 3) * 8];
    float* mrow = mg + (size_t)n * 6272;   // [196][32]
    double s = 0.0, q = 0.0;
    #pragma unroll
    for (int k = 0; k < 7; ++k) {
        float4 n0 = X4[(2 * py + 0) * 8 + k + 1];
        float4 n1 = X4[(2 * py + 1) * 8 + k + 1];
        float4 n2 = X4[(2 * py + 2) * 8 + k + 1];
        float4 n3 = X4[(2 * py + 3) * 8 + k + 1];
        float a[4][6];
        a[0][0] = cur0.x; a[0][1] = cur0.y; a[0][2] = cur0.z; a[0][3] = cur0.w; a[0][4] = n0.x; a[0][5] = n0.y;
        a[1][0] = cur1.x; a[1][1] = cur1.y; a[1][2] = cur1.z; a[1][3] = cur1.w; a[1][4] = n1.x; a[1][5] = n1.y;
        a[2][0] = cur2.x; a[2][1] = cur2.y; a[2][2] = cur2.z; a[2][3] = cur2.w; a[2][4] = n2.x; a[2][5] = n2.y;
        a[3][0] = cur3.x; a[3][1] = cur3.y; a[3][2] = cur3.z; a[3][3] = cur3.w; a[3][4] = n3.x; a[3][5] = n3.y;
        #pragma unroll
        for (int e = 0; e < 2; ++e) {
            int base = 2 * e;
            float s00 = 0.f, s01 = 0.f, s10 = 0.f, s11 = 0.f;
            #pragma unroll
            for (int ky = 0; ky < 3; ++ky)
            #pragma unroll
            for (int kx = 0; kx < 3; ++kx) {
                float w = wreg[ky * 3 + kx];
                s00 = fmaf(a[ky][base + kx], w, s00);
                s01 = fmaf(a[ky][base + kx + 1], w, s01);
                s10 = fmaf(a[ky + 1][base + kx], w, s10);
                s11 = fmaf(a[ky + 1][base + kx + 1], w, s11);
            }
            float m = fmaxf(fmaxf(s00, s01), fmaxf(s10, s11));
            int pix = py * 14 + 2 * k + e;
            mrow[pix * 32 + c] = m;
            double v = (double)m;
            s += v; q += v * v;
        }
        cur0 = n0; cur1 = n1; cur2 = n2; cur3 = n3;
    }
    rs[c * 14 + py] = s; rq[c * 14 + py] = q;
    __syncthreads();
    if (t < 32) {
        double S = 0.0, Q = 0.0;
        #pragma unroll
        for (int i = 0; i < 14; ++i) { S += rs[t * 14 + i]; Q += rq[t * 14 + i]; }
        part0[(size_t)t * 4096 + n] = S;
        part0[(size_t)32 * 4096 + (size_t)t * 4096 + n] = Q;
    }
}

// ---------------------------------------------------------------------------
// finalize: grid(32) x 256 threads. Block = channel. Fixed-order reduction
// of G partials, layout part[c*G+i] / part[32G+c*G+i]; coalesced; double.
// ---------------------------------------------------------------------------
__global__ __launch_bounds__(256) void k_finalize(const double* __restrict__ part, int G,
                                                  const float* __restrict__ g,
                                                  const float* __restrict__ b,
                                                  double inv_count, float* __restrict__ ss) {
    int c = blockIdx.x, t = threadIdx.x;
    double s = 0.0, q = 0.0;
    for (int i = t; i < G; i += 256) {
        s += part[(size_t)c * G + i];
        q += part[(size_t)32 * G + (size_t)c * G + i];
    }
    #pragma unroll
    for (int o = 32; o > 0; o >>= 1) { s += __shfl_down(s, o); q += __shfl_down(q, o); }
    __shared__ double rs[4], rq[4];
    int w = t >> 6, l = t & 63;
    if (l == 0) { rs[w] = s; rq[w] = q; }
    __syncthreads();
    if (t == 0) {
        s = rs[0] + rs[1] + rs[2] + rs[3];
        q = rq[0] + rq[1] + rq[2] + rq[3];
        double mean = s * inv_count;
        double var = q * inv_count - mean * mean;
        double sc = (double)g[c] / sqrt(var + 1e-5);
        ss[c] = (float)sc;
        ss[32 + c] = (float)((double)b[c] - mean * sc);
    }
}

// ---------------------------------------------------------------------------
// conv1s: bf16 MFMA implicit GEMM, 2 images/block. Staging builds the
// pre-swizzled sign image DIRECTLY from m + BN0 coeffs. Thread (u=t>>2,
// tq=t&3) owns channels tq*8..tq*8+7 and writes word qd = tq ^ psw(pl) --
// identical content to the old s0b format (g = qd ^ psw <=> tq = g).
// MFMA phase unchanged from the verified conv1m.
// ---------------------------------------------------------------------------
__global__ __launch_bounds__(256) void k_conv1s(const float* __restrict__ m,
                                                const float* __restrict__ ss,
                                                const uint16_t* __restrict__ w1f,
                                                float* __restrict__ p1,
                                                double* __restrict__ part1) {
    __shared__ uint32_t lds[8192];   // 32 KB, 2 x 4096 words
    int t = threadIdx.x;
    int n0 = blockIdx.x * 2;
    int lane = t & 63, wv = t >> 6;
    int q = lane >> 5, ncol = lane & 31;
    v8s wfr[18];
    #pragma unroll
    for (int f = 0; f < 18; ++f)
        wfr[f] = *(const v8s*)(w1f + (f * 2 + q) * 256 + ncol * 8);

    // halo zero words (same 60-pixel edge mapping as the old bn0r emit)
    uint4 z4; z4.x = z4.y = z4.z = z4.w = 0u;
    for (int i = t; i < 480; i += 256) {
        int img = (i >= 240) ? 1 : 0;
        int e2 = i - img * 240;
        int e = e2 >> 2, qd = e2 & 3;
        int yh, xh;
        if (e < 16)      { yh = 0;      xh = e; }
        else if (e < 32) { yh = 15;     xh = e - 16; }
        else if (e < 46) { yh = e - 31; xh = 0; }
        else             { yh = e - 45; xh = 15; }
        *(uint4*)&lds[img * 4096 + (yh * 16 + xh) * 16 + qd * 4] = z4;
    }
    // data words: BN + sign from m
    int u = t >> 2, tq = t & 3;
    float sc8[8], sh8[8];
    #pragma unroll
    for (int j = 0; j < 8; ++j) { sc8[j] = ss[tq * 8 + j]; sh8[j] = ss[32 + tq * 8 + j]; }
    for (int pg = u; pg < 392; pg += 64) {
        int img = (pg >= 196) ? 1 : 0;
        int pl = pg - img * 196;
        int iy = pl / 14, ix = pl - iy * 14;
        int yy = iy + 1, xx2 = ix + 1;
        int p = yy * 16 + xx2;
        int psw = (xx2 & 3) ^ (yy & 3);
        int qd = tq ^ psw;
        const float4* mp = (const float4*)(m + ((size_t)(n0 + img) * 196 + pl) * 32 + tq * 8);
        float4 v0 = mp[0], v1 = mp[1];
        float h[8];
        h[0] = fmaf(sc8[0], v0.x, sh8[0]); h[1] = fmaf(sc8[1], v0.y, sh8[1]);
        h[2] = fmaf(sc8[2], v0.z, sh8[2]); h[3] = fmaf(sc8[3], v0.w, sh8[3]);
        h[4] = fmaf(sc8[4], v1.x, sh8[4]); h[5] = fmaf(sc8[5], v1.y, sh8[5]);
        h[6] = fmaf(sc8[6], v1.z, sh8[6]); h[7] = fmaf(sc8[7], v1.w, sh8[7]);
        uint32_t d[4];
        #pragma unroll
        for (int j = 0; j < 4; ++j) {
            float h0 = h[2 * j], h1 = h[2 * j + 1];
            uint32_t b0 = (h0 > 0.f) ? 0x3F80u : ((h0 < 0.f) ? 0xBF80u : 0u);
            uint32_t b1 = (h1 > 0.f) ? 0x3F80u : ((h1 < 0.f) ? 0xBF80u : 0u);
            d[j] = b0 | (b1 << 16);
        }
        uint4 v; v.x = d[0]; v.y = d[1]; v.z = d[2]; v.w = d[3];
        *(uint4*)&lds[img * 4096 + p * 16 + qd * 4] = v;
    }
    __syncthreads();

    // ---- MFMA phase (unchanged from old conv1m) ----
    int img = wv >> 1, wh = wv & 1;
    int n = n0 + img;
    int ibase = img * 4096;
    int mm = lane & 31;
    int quad = mm & 3, pwl = mm >> 2;
    int dy = quad >> 1, dx = quad & 1;
    double sAcc = 0.0, qAcc = 0.0;
    for (int tile = wh; tile < 7; tile += 2) {
        int pw = tile * 8 + pwl;
        int pwc = min(pw, 48);
        int py = pwc / 7, px = pwc - py * 7;
        int pbase = (2 * py + dy) * 16 + 2 * px + dx;
        v16f acc;
        #pragma unroll
        for (int i = 0; i < 16; ++i) acc[i] = 0.f;
        #pragma unroll
        for (int tp = 0; tp < 9; ++tp) {
            int p = pbase + (tp / 3) * 16 + (tp % 3);
            int psw = (p ^ (p >> 4)) & 3;
            #pragma unroll
            for (int kh = 0; kh < 2; ++kh) {
                int g = kh * 2 + q;
                int idx = ibase + p * 16 + ((g ^ psw) << 2);
                v8s a = *(const v8s*)&lds[idx];
                acc = __builtin_amdgcn_mfma_f32_32x32x16_bf16(a, wfr[tp * 2 + kh], acc, 0, 0, 0);
            }
        }
        #pragma unroll
        for (int g4 = 0; g4 < 4; ++g4) {
            float mx = fmaxf(fmaxf(acc[4 * g4], acc[4 * g4 + 1]),
                             fmaxf(acc[4 * g4 + 2], acc[4 * g4 + 3]));
            int pwo = tile * 8 + 2 * g4 + q;
            if (pwo < 49) {
                p1[((size_t)n * 49 + pwo) * 32 + ncol] = mx;
                double v = (double)mx;
                sAcc += v; qAcc += v * v;
            }
        }
    }
    __syncthreads();
    double* red = (double*)lds;
    red[(wv * 2 + q) * 32 + ncol] = sAcc;
    red[256 + (wv * 2 + q) * 32 + ncol] = qAcc;
    __syncthreads();
    if (t < 32) {
        double S = 0.0, Q = 0.0;
        #pragma unroll
        for (int i = 0; i < 8; ++i) { S += red[i * 32 + t]; Q += red[256 + i * 32 + t]; }
        part1[(size_t)t * 2048 + blockIdx.x] = S;
        part1[(size_t)32 * 2048 + (size_t)t * 2048 + blockIdx.x] = Q;
    }
}

// ---------------------------------------------------------------------------
// bc2m: FUSED bn1 + conv2m, 8 images/block. R6: WAVE-LOCAL staging -- each
// wave owns 2 images and a private Hw quarter; block barriers during staging
// (16 of them) replaced by in-wave s_waitcnt lgkmcnt(0) fences (lockstep wave
// => only memory ordering needed). All VALUES bit-identical to R5: H
// expression, pooling max/min+select, pack mapping, hp1 fmax tree, MFMA
// phase. Only the thread->work assignment changed (disjoint destinations).
// LDS: 32KB act + 25.1KB Hw = 57.9KB -> still 2 blocks/CU (grid=512 gives
// only 2 blocks/CU anyway).
// ---------------------------------------------------------------------------
__global__ __launch_bounds__(256) void k_bc2m(const float* __restrict__ p1,
                                              const float* __restrict__ m,
                                              const float* __restrict__ ss,
                                              const uint16_t* __restrict__ w2f,
                                              float* __restrict__ p2,
                                              float* __restrict__ hp1,
                                              double* __restrict__ part2) {
    __shared__ uint32_t lds[8192];     // 32 KB act image, 8 x 1024 words
    __shared__ float Hw[4][1568];      // per-wave H scratch (25.1 KB)
    int t = threadIdx.x;
    int n0 = blockIdx.x * 8;
    int lane = t & 63, wv = t >> 6;
    int q = lane >> 5, ncol = lane & 31;

    // per-lane BN coeffs for its fixed channel quad: e = lane + 64k => e&7
    // is lane-invariant (64 ≡ 0 mod 8), so cq = lane&7 covers channels
    // cq*4 .. cq*4+3 for every element this lane stages.
    int cq = lane & 7;
    float sc1v[4], sh1v[4], sc0v[4], sh0v[4];
    #pragma unroll
    for (int j = 0; j < 4; ++j) {
        sc1v[j] = ss[64 + cq * 4 + j]; sh1v[j] = ss[96 + cq * 4 + j];
        sc0v[j] = ss[cq * 4 + j];      sh0v[j] = ss[32 + cq * 4 + j];
    }

    float4* H4 = (float4*)Hw[wv];
    float* Hp = Hw[wv];
    #pragma unroll
    for (int sIt = 0; sIt < 2; ++sIt) {
        int img = 2 * wv + sIt;
        int n = n0 + img;
        const float4* P4 = (const float4*)(p1 + (size_t)n * 1568);
        const float4* M4 = (const float4*)(m + (size_t)n * 6272);
        if (sIt) {
            // previous image's pack/hp1 LDS reads must have returned before
            // we overwrite Hw (lockstep wave: program order + lgkmcnt drain).
            asm volatile("s_waitcnt lgkmcnt(0)" ::: "memory");
            __builtin_amdgcn_sched_barrier(0);
        }
        // H = bn1(p1) + hp0, hp0 = fmaf(sc0, sc0>0 ? max4(m) : min4(m), sh0)
        for (int e = lane; e < 392; e += 64) {
            int pix = e >> 3;
            int py = pix / 7, px = pix - py * 7;
            int mb = ((2 * py) * 14 + 2 * px) * 8 + cq;
            float4 a0 = M4[mb], a1 = M4[mb + 8], a2 = M4[mb + 112], a3 = M4[mb + 120];
            float4 pv = P4[e];
            float mx0 = fmaxf(fmaxf(a0.x, a1.x), fmaxf(a2.x, a3.x));
            float mx1 = fmaxf(fmaxf(a0.y, a1.y), fmaxf(a2.y, a3.y));
            float mx2 = fmaxf(fmaxf(a0.z, a1.z), fmaxf(a2.z, a3.z));
            float mx3 = fmaxf(fmaxf(a0.w, a1.w), fmaxf(a2.w, a3.w));
            float mn0 = fminf(fminf(a0.x, a1.x), fminf(a2.x, a3.x));
            float mn1 = fminf(fminf(a0.y, a1.y), fminf(a2.y, a3.y));
            float mn2 = fminf(fminf(a0.z, a1.z), fminf(a2.z, a3.z));
            float mn3 = fminf(fminf(a0.w, a1.w), fminf(a2.w, a3.w));
            float s0 = (sc0v[0] > 0.f) ? mx0 : mn0;
            float s1 = (sc0v[1] > 0.f) ? mx1 : mn1;
            float s2 = (sc0v[2] > 0.f) ? mx2 : mn2;
            float s3 = (sc0v[3] > 0.f) ? mx3 : mn3;
            float4 hv;
            hv.x = fmaf(sc1v[0], pv.x, sh1v[0]) + fmaf(sc0v[0], s0, sh0v[0]);
            hv.y = fmaf(sc1v[1], pv.y, sh1v[1]) + fmaf(sc0v[1], s1, sh0v[1]);
            hv.z = fmaf(sc1v[2], pv.z, sh1v[2]) + fmaf(sc0v[2], s2, sh0v[2]);
            hv.w = fmaf(sc1v[3], pv.w, sh1v[3]) + fmaf(sc0v[3], s3, sh0v[3]);
            H4[e] = hv;
        }
        // drain H writes so all lanes' values are readable (in-wave fence)
        asm volatile("s_waitcnt lgkmcnt(0)" ::: "memory");
        __builtin_amdgcn_sched_barrier(0);
        // pack act words (identical mapping to the verified k_bn1 sp[i])
        uint32_t* ap = &lds[img * 1024];
        for (int i = lane; i < 1024; i += 64) {
            int pp = i >> 4, r = i & 15;
            int y = pp >> 3, xq = pp & 7;
            uint32_t d = 0u;
            if (y >= 1 && xq >= 1) {
                int pix = (y - 1) * 7 + (xq - 1);
                int sub = r & 3;
                int g = (r >> 2) ^ (pp & 3);
                int c0 = ((g << 2) | sub) * 2;
                float h0 = Hp[pix * 32 + c0];
                float h1 = Hp[pix * 32 + c0 + 1];
                uint32_t w0b = (h0 > 0.f) ? 0x3F80u : ((h0 < 0.f) ? 0xBF80u : 0u);
                uint32_t w1b = (h1 > 0.f) ? 0x3F80u : ((h1 < 0.f) ? 0xBF80u : 0u);
                d = w0b | (w1b << 16);
            }
            ap[i] = d;
        }
        // hp1 (identical fmax tree / dest layout)
        for (int jj = lane; jj < 288; jj += 64) {
            int c = jj / 9, pix = jj - c * 9;
            int r = pix / 3, qq = pix - r * 3;
            float e0 = Hp[((2 * r) * 7 + 2 * qq) * 32 + c];
            float e1 = Hp[((2 * r) * 7 + 2 * qq + 1) * 32 + c];
            float e2 = Hp[((2 * r + 1) * 7 + 2 * qq) * 32 + c];
            float e3 = Hp[((2 * r + 1) * 7 + 2 * qq + 1) * 32 + c];
            hp1[(size_t)n * 288 + c * 9 + pix] = fmaxf(fmaxf(e0, e1), fmaxf(e2, e3));
        }
    }
    __syncthreads();   // all act words visible to all waves

    // weights loaded after staging (reduces concurrent VGPR pressure)
    v8s wfr[18];
    #pragma unroll
    for (int f = 0; f < 18; ++f)
        wfr[f] = *(const v8s*)(w2f + (f * 2 + q) * 256 + ncol * 8);

    // ---- conv2m MFMA phase (unchanged) ----
    int mmm = lane & 31;
    int quad = mmm & 3, pwl = mmm >> 2;
    int dy = quad >> 1, dx = quad & 1;
    double sAcc = 0.0, qAcc = 0.0;
    for (int tile = wv; tile < 9; tile += 4) {
        int pwg = tile * 8 + pwl;
        int img = pwg / 9, pwi = pwg - img * 9;
        int py = pwi / 3, px = pwi - py * 3;
        int pbase = (2 * py + dy) * 8 + 2 * px + dx;
        v16f acc;
        #pragma unroll
        for (int i = 0; i < 16; ++i) acc[i] = 0.f;
        #pragma unroll
        for (int tp = 0; tp < 9; ++tp) {
            int p = pbase + (tp / 3) * 8 + (tp % 3);
            int psw = p & 3;
            #pragma unroll
            for (int kh = 0; kh < 2; ++kh) {
                int g = kh * 2 + q;
                int idx = img * 1024 + p * 16 + ((g ^ psw) << 2);
                v8s a = *(const v8s*)&lds[idx];
                acc = __builtin_amdgcn_mfma_f32_32x32x16_bf16(a, wfr[tp * 2 + kh], acc, 0, 0, 0);
            }
        }
        #pragma unroll
        for (int g4 = 0; g4 < 4; ++g4) {
            float mx = fmaxf(fmaxf(acc[4 * g4], acc[4 * g4 + 1]),
                             fmaxf(acc[4 * g4 + 2], acc[4 * g4 + 3]));
            int pwo = tile * 8 + 2 * g4 + q;
            int oimg = pwo / 9, opwi = pwo - oimg * 9;
            p2[(size_t)(n0 + oimg) * 288 + ncol * 9 + opwi] = mx;
            double v = (double)mx;
            sAcc += v; qAcc += v * v;
        }
    }
    __syncthreads();
    double* red = (double*)lds;
    red[(wv * 2 + q) * 32 + ncol] = sAcc;
    red[256 + (wv * 2 + q) * 32 + ncol] = qAcc;
    __syncthreads();
    if (t < 32) {
        double S = 0.0, Q = 0.0;
        #pragma unroll
        for (int i = 0; i < 8; ++i) { S += red[i * 32 + t]; Q += red[256 + i * 32 + t]; }
        part2[(size_t)t * 512 + blockIdx.x] = S;
        part2[(size_t)32 * 512 + (size_t)t * 512 + blockIdx.x] = Q;
    }
}

// ---------------------------------------------------------------------------
// FC: out[n,k] = sum_j (bn2(p2)+hp1)[n,j] * fw[k,j] + fb[k].  Wave per image.
// ---------------------------------------------------------------------------
__global__ __launch_bounds__(256) void k_fc(const float* __restrict__ p2,
                                            const float* __restrict__ hp1,
                                            const float* __restrict__ ss,
                                            const float* __restrict__ fw,
                                            const float* __restrict__ fb,
                                            float* __restrict__ outv) {
    int wv = threadIdx.x >> 6, l = threadIdx.x & 63;
    int n = blockIdx.x * 4 + wv;
    float acc[10];
    #pragma unroll
    for (int k = 0; k < 10; ++k) acc[k] = 0.f;
    #pragma unroll
    for (int i = 0; i < 5; ++i) {
        int j = l + 64 * i;
        if (j < 288) {
            int c = j / 9;
            float h = fmaf(ss[128 + c], p2[n * 288 + j], ss[160 + c]) + hp1[n * 288 + j];
            #pragma unroll
            for (int k = 0; k < 10; ++k)
                acc[k] = fmaf(h, fw[k * 288 + j], acc[k]);
        }
    }
    #pragma unroll
    for (int k = 0; k < 10; ++k) {
        float s = acc[k];
        #pragma unroll
        for (int o = 32; o > 0; o >>= 1) s += __shfl_down(s, o);
        if (l == 0) outv[n * 10 + k] = s + fb[k];
    }
}

// ---------------------------------------------------------------------------
// Workspace layout (bytes) -- FULLY DISJOINT, no overlays, peak 141.3 MB:
//   ss    @1024      (768 B)
//   w1f   @2048      (18,432)       ends 20,480
//   w2f   @20480     (18,432)       ends 38,912
//   part1 @38912     (1,048,576)    ends 1,087,488
//   part0 @1087488   (2,097,152)    ends 3,184,640
//   p1    @3184640   (25,690,112)   ends 28,874,752
//   p2    @28874752  (4,718,592)    ends 33,593,344
//   hp1   @33593344  (4,718,592)    ends 38,311,936
//   part2 @38311936  (262,144)      ends 38,574,080
//   m     @38574080  (102,760,448)  ends 141,334,528
// 7 kernel nodes. Kernel-boundary ordering is the only cross-block sync.
// ---------------------------------------------------------------------------
extern "C" void kernel_launch(void* const* d_in, const int* in_sizes, int n_in,
                              void* d_out, int out_size, void* d_ws, size_t ws_size,
                              hipStream_t stream) {
    (void)in_sizes; (void)n_in; (void)out_size; (void)ws_size;
    const float* x  = (const float*)d_in[0];
    const float* w0 = (const float*)d_in[1];
    const float* g0 = (const float*)d_in[2];
    const float* b0 = (const float*)d_in[3];
    const float* w1 = (const float*)d_in[4];
    const float* g1 = (const float*)d_in[5];
    const float* b1 = (const float*)d_in[6];
    const float* w2 = (const float*)d_in[7];
    const float* g2 = (const float*)d_in[8];
    const float* b2 = (const float*)d_in[9];
    const float* fw = (const float*)d_in[10];
    const float* fb = (const float*)d_in[11];
    float* outv = (float*)d_out;
    char* ws = (char*)d_ws;

    float*     ss    = (float*)(ws + 1024);
    uint16_t*  w1f   = (uint16_t*)(ws + 2048);
    uint16_t*  w2f   = (uint16_t*)(ws + 20480);
    double*    part1 = (double*)(ws + 38912);
    double*    part0 = (double*)(ws + 1087488);
    float*     p1    = (float*)(ws + 3184640);
    float*     p2    = (float*)(ws + 28874752);
    float*     hp1   = (float*)(ws + 33593344);
    double*    part2 = (double*)(ws + 38311936);
    float*     m     = (float*)(ws + 38574080);

    k_conv0f<<<BATCH, 448, 0, stream>>>(x, w0, w1, w2, w1f, w2f, part0, m);
    k_finalize<<<32, 256, 0, stream>>>(part0, 4096, g0, b0, 1.0 / (BATCH * 196.0), ss);

    k_conv1s<<<BATCH / 2, 256, 0, stream>>>(m, ss, w1f, p1, part1);
    k_finalize<<<32, 256, 0, stream>>>(part1, 2048, g1, b1, 1.0 / (BATCH * 49.0), ss + 64);

    k_bc2m<<<BATCH / 8, 256, 0, stream>>>(p1, m, ss, w2f, p2, hp1, part2);
    k_finalize<<<32, 256, 0, stream>>>(part2, 512, g2, b2, 1.0 / (BATCH * 9.0), ss + 128);

    k_fc<<<BATCH / 4, 256, 0, stream>>>(p2, hp1, ss, fw, fb, outv);
}

// Round 7
// 184.918 us; speedup vs baseline: 1.0398x; 1.0398x over previous
//
#include <hip/hip_runtime.h>
#include <stdint.h>

#define BATCH 4096

typedef float v16f __attribute__((ext_vector_type(16)));
typedef short v8s  __attribute__((ext_vector_type(8)));

// ---------------------------------------------------------------------------
// conv0f2: conv0 pass, 2 IMAGES PER BLOCK interleaved for ILP (R7).
// Per-image FMA order, fmax tree, f64 stats order, m-store addresses and
// part0 reduction order are IDENTICAL to the verified R5 k_conv0f -- the two
// images are independent dependence streams interleaved instruction-wise.
// FROZEN per image: conv FMA order AND stats accumulation order.
// ---------------------------------------------------------------------------
__global__ __launch_bounds__(448) void k_conv0f2(const float* __restrict__ x,
                                                 const float* __restrict__ w0,
                                                 const float* __restrict__ w1,
                                                 const float* __restrict__ w2,
                                                 uint16_t* __restrict__ w1f,
                                                 uint16_t* __restrict__ w2f,
                                                 double* __restrict__ part0,
                                                 float* __restrict__ mg) {
    __shared__ float xsA[960], xsB[960];   // 30 rows x 32 cols (zero halo)
    __shared__ float wl[288];
    __shared__ double rs[896], rq[896];    // [im*448 + c*14+py]
    int t = threadIdx.x;
    int nA = blockIdx.x * 2, nB = nA + 1;

    if (blockIdx.x < 72 && t < 256) {
        int i = blockIdx.x * 256 + t;
        int ii = (i < 9216) ? i : i - 9216;
        const float* w = (i < 9216) ? w1 : w2;
        uint16_t* o = (i < 9216) ? w1f : w2f;
        int j = ii & 7, nn = (ii >> 3) & 31, q2 = (ii >> 8) & 1, kh = (ii >> 9) & 1, tp = ii >> 10;
        int cin = kh * 16 + q2 * 8 + j;
        float v = w[(nn * 32 + cin) * 9 + tp];
        o[ii] = (v > 0.f) ? 0x3F80 : ((v < 0.f) ? 0xBF80 : 0);
    }

    for (int i = t; i < 960; i += 448) { xsA[i] = 0.f; xsB[i] = 0.f; }
    for (int i = t; i < 288; i += 448) wl[i] = w0[i];
    __syncthreads();
    for (int i = t; i < 784; i += 448) {
        int y = i / 28, xx = i - y * 28;
        xsA[(y + 1) * 32 + xx + 1] = x[nA * 784 + i];
        xsB[(y + 1) * 32 + xx + 1] = x[nB * 784 + i];
    }
    __syncthreads();
    int c = t & 31, py = t >> 5;
    float wreg[9];
    #pragma unroll
    for (int i = 0; i < 9; ++i) wreg[i] = wl[c * 9 + i];
    const float4* XA = (const float4*)xsA;
    const float4* XB = (const float4*)xsB;
    float4 cA0 = XA[(2 * py + 0) * 8];
    float4 cA1 = XA[(2 * py + 1) * 8];
    float4 cA2 = XA[(2 * py + 2) * 8];
    float4 cA3 = XA[(2 * py + 3) * 8];
    float4 cB0 = XB[(2 * py + 0) * 8];
    float4 cB1 = XB[(2 * py + 1) * 8];
    float4 cB2 = XB[(2 * py + 2) * 8];
    float4 cB3 = XB[(2 * py + 3) * 8];
    float* mrA = mg + (size_t)nA * 6272;   // [196][32]
    float* mrB = mg + (size_t)nB * 6272;
    double sA = 0.0, qA = 0.0, sB = 0.0, qB = 0.0;
    #pragma unroll
    for (int k = 0; k < 7; ++k) {
        float4 nA0 = XA[(2 * py + 0) * 8 + k + 1];
        float4 nA1 = XA[(2 * py + 1) * 8 + k + 1];
        float4 nA2 = XA[(2 * py + 2) * 8 + k + 1];
        float4 nA3 = XA[(2 * py + 3) * 8 + k + 1];
        float4 nB0 = XB[(2 * py + 0) * 8 + k + 1];
        float4 nB1 = XB[(2 * py + 1) * 8 + k + 1];
        float4 nB2 = XB[(2 * py + 2) * 8 + k + 1];
        float4 nB3 = XB[(2 * py + 3) * 8 + k + 1];
        float aA[4][6], aB[4][6];
        aA[0][0] = cA0.x; aA[0][1] = cA0.y; aA[0][2] = cA0.z; aA[0][3] = cA0.w; aA[0][4] = nA0.x; aA[0][5] = nA0.y;
        aA[1][0] = cA1.x; aA[1][1] = cA1.y; aA[1][2] = cA1.z; aA[1][3] = cA1.w; aA[1][4] = nA1.x; aA[1][5] = nA1.y;
        aA[2][0] = cA2.x; aA[2][1] = cA2.y; aA[2][2] = cA2.z; aA[2][3] = cA2.w; aA[2][4] = nA2.x; aA[2][5] = nA2.y;
        aA[3][0] = cA3.x; aA[3][1] = cA3.y; aA[3][2] = cA3.z; aA[3][3] = cA3.w; aA[3][4] = nA3.x; aA[3][5] = nA3.y;
        aB[0][0] = cB0.x; aB[0][1] = cB0.y; aB[0][2] = cB0.z; aB[0][3] = cB0.w; aB[0][4] = nB0.x; aB[0][5] = nB0.y;
        aB[1][0] = cB1.x; aB[1][1] = cB1.y; aB[1][2] = cB1.z; aB[1][3] = cB1.w; aB[1][4] = nB1.x; aB[1][5] = nB1.y;
        aB[2][0] = cB2.x; aB[2][1] = cB2.y; aB[2][2] = cB2.z; aB[2][3] = cB2.w; aB[2][4] = nB2.x; aB[2][5] = nB2.y;
        aB[3][0] = cB3.x; aB[3][1] = cB3.y; aB[3][2] = cB3.z; aB[3][3] = cB3.w; aB[3][4] = nB3.x; aB[3][5] = nB3.y;
        #pragma unroll
        for (int e = 0; e < 2; ++e) {
            int base = 2 * e;
            float sA00 = 0.f, sA01 = 0.f, sA10 = 0.f, sA11 = 0.f;
            float sB00 = 0.f, sB01 = 0.f, sB10 = 0.f, sB11 = 0.f;
            #pragma unroll
            for (int ky = 0; ky < 3; ++ky)
            #pragma unroll
            for (int kx = 0; kx < 3; ++kx) {
                float w = wreg[ky * 3 + kx];
                sA00 = fmaf(aA[ky][base + kx], w, sA00);
                sA01 = fmaf(aA[ky][base + kx + 1], w, sA01);
                sA10 = fmaf(aA[ky + 1][base + kx], w, sA10);
                sA11 = fmaf(aA[ky + 1][base + kx + 1], w, sA11);
                sB00 = fmaf(aB[ky][base + kx], w, sB00);
                sB01 = fmaf(aB[ky][base + kx + 1], w, sB01);
                sB10 = fmaf(aB[ky + 1][base + kx], w, sB10);
                sB11 = fmaf(aB[ky + 1][base + kx + 1], w, sB11);
            }
            float mA = fmaxf(fmaxf(sA00, sA01), fmaxf(sA10, sA11));
            float mB = fmaxf(fmaxf(sB00, sB01), fmaxf(sB10, sB11));
            int pix = py * 14 + 2 * k + e;
            mrA[pix * 32 + c] = mA;
            mrB[pix * 32 + c] = mB;
            double vA = (double)mA, vB = (double)mB;
            sA += vA; qA += vA * vA;
            sB += vB; qB += vB * vB;
        }
        cA0 = nA0; cA1 = nA1; cA2 = nA2; cA3 = nA3;
        cB0 = nB0; cB1 = nB1; cB2 = nB2; cB3 = nB3;
    }
    rs[c * 14 + py] = sA; rq[c * 14 + py] = qA;
    rs[448 + c * 14 + py] = sB; rq[448 + c * 14 + py] = qB;
    __syncthreads();
    if (t < 32) {
        double SA = 0.0, QA = 0.0;
        #pragma unroll
        for (int i = 0; i < 14; ++i) { SA += rs[t * 14 + i]; QA += rq[t * 14 + i]; }
        part0[(size_t)t * 4096 + nA] = SA;
        part0[(size_t)32 * 4096 + (size_t)t * 4096 + nA] = QA;
        double SB = 0.0, QB = 0.0;
        #pragma unroll
        for (int i = 0; i < 14; ++i) { SB += rs[448 + t * 14 + i]; QB += rq[448 + t * 14 + i]; }
        part0[(size_t)t * 4096 + nB] = SB;
        part0[(size_t)32 * 4096 + (size_t)t * 4096 + nB] = QB;
    }
}

// ---------------------------------------------------------------------------
// finalize: grid(32) x 256 threads. Block = channel. Fixed-order reduction
// of G partials, layout part[c*G+i] / part[32G+c*G+i]; coalesced; double.
// ---------------------------------------------------------------------------
__global__ __launch_bounds__(256) void k_finalize(const double* __restrict__ part, int G,
                                                  const float* __restrict__ g,
                                                  const float* __restrict__ b,
                                                  double inv_count, float* __restrict__ ss) {
    int c = blockIdx.x, t = threadIdx.x;
    double s = 0.0, q = 0.0;
    for (int i = t; i < G; i += 256) {
        s += part[(size_t)c * G + i];
        q += part[(size_t)32 * G + (size_t)c * G + i];
    }
    #pragma unroll
    for (int o = 32; o > 0; o >>= 1) { s += __shfl_down(s, o); q += __shfl_down(q, o); }
    __shared__ double rs[4], rq[4];
    int w = t >> 6, l = t & 63;
    if (l == 0) { rs[w] = s; rq[w] = q; }
    __syncthreads();
    if (t == 0) {
        s = rs[0] + rs[1] + rs[2] + rs[3];
        q = rq[0] + rq[1] + rq[2] + rq[3];
        double mean = s * inv_count;
        double var = q * inv_count - mean * mean;
        double sc = (double)g[c] / sqrt(var + 1e-5);
        ss[c] = (float)sc;
        ss[32 + c] = (float)((double)b[c] - mean * sc);
    }
}

// ---------------------------------------------------------------------------
// conv1s: bf16 MFMA implicit GEMM, 2 images/block. Staging builds the
// pre-swizzled sign image DIRECTLY from m + BN0 coeffs. Thread (u=t>>2,
// tq=t&3) owns channels tq*8..tq*8+7 and writes word qd = tq ^ psw(pl) --
// identical content to the old s0b format (g = qd ^ psw <=> tq = g).
// MFMA phase unchanged from the verified conv1m.  (verbatim R5)
// ---------------------------------------------------------------------------
__global__ __launch_bounds__(256) void k_conv1s(const float* __restrict__ m,
                                                const float* __restrict__ ss,
                                                const uint16_t* __restrict__ w1f,
                                                float* __restrict__ p1,
                                                double* __restrict__ part1) {
    __shared__ uint32_t lds[8192];   // 32 KB, 2 x 4096 words
    int t = threadIdx.x;
    int n0 = blockIdx.x * 2;
    int lane = t & 63, wv = t >> 6;
    int q = lane >> 5, ncol = lane & 31;
    v8s wfr[18];
    #pragma unroll
    for (int f = 0; f < 18; ++f)
        wfr[f] = *(const v8s*)(w1f + (f * 2 + q) * 256 + ncol * 8);

    // halo zero words (same 60-pixel edge mapping as the old bn0r emit)
    uint4 z4; z4.x = z4.y = z4.z = z4.w = 0u;
    for (int i = t; i < 480; i += 256) {
        int img = (i >= 240) ? 1 : 0;
        int e2 = i - img * 240;
        int e = e2 >> 2, qd = e2 & 3;
        int yh, xh;
        if (e < 16)      { yh = 0;      xh = e; }
        else if (e < 32) { yh = 15;     xh = e - 16; }
        else if (e < 46) { yh = e - 31; xh = 0; }
        else             { yh = e - 45; xh = 15; }
        *(uint4*)&lds[img * 4096 + (yh * 16 + xh) * 16 + qd * 4] = z4;
    }
    // data words: BN + sign from m
    int u = t >> 2, tq = t & 3;
    float sc8[8], sh8[8];
    #pragma unroll
    for (int j = 0; j < 8; ++j) { sc8[j] = ss[tq * 8 + j]; sh8[j] = ss[32 + tq * 8 + j]; }
    for (int pg = u; pg < 392; pg += 64) {
        int img = (pg >= 196) ? 1 : 0;
        int pl = pg - img * 196;
        int iy = pl / 14, ix = pl - iy * 14;
        int yy = iy + 1, xx2 = ix + 1;
        int p = yy * 16 + xx2;
        int psw = (xx2 & 3) ^ (yy & 3);
        int qd = tq ^ psw;
        const float4* mp = (const float4*)(m + ((size_t)(n0 + img) * 196 + pl) * 32 + tq * 8);
        float4 v0 = mp[0], v1 = mp[1];
        float h[8];
        h[0] = fmaf(sc8[0], v0.x, sh8[0]); h[1] = fmaf(sc8[1], v0.y, sh8[1]);
        h[2] = fmaf(sc8[2], v0.z, sh8[2]); h[3] = fmaf(sc8[3], v0.w, sh8[3]);
        h[4] = fmaf(sc8[4], v1.x, sh8[4]); h[5] = fmaf(sc8[5], v1.y, sh8[5]);
        h[6] = fmaf(sc8[6], v1.z, sh8[6]); h[7] = fmaf(sc8[7], v1.w, sh8[7]);
        uint32_t d[4];
        #pragma unroll
        for (int j = 0; j < 4; ++j) {
            float h0 = h[2 * j], h1 = h[2 * j + 1];
            uint32_t b0 = (h0 > 0.f) ? 0x3F80u : ((h0 < 0.f) ? 0xBF80u : 0u);
            uint32_t b1 = (h1 > 0.f) ? 0x3F80u : ((h1 < 0.f) ? 0xBF80u : 0u);
            d[j] = b0 | (b1 << 16);
        }
        uint4 v; v.x = d[0]; v.y = d[1]; v.z = d[2]; v.w = d[3];
        *(uint4*)&lds[img * 4096 + p * 16 + qd * 4] = v;
    }
    __syncthreads();

    // ---- MFMA phase (unchanged from old conv1m) ----
    int img = wv >> 1, wh = wv & 1;
    int n = n0 + img;
    int ibase = img * 4096;
    int mm = lane & 31;
    int quad = mm & 3, pwl = mm >> 2;
    int dy = quad >> 1, dx = quad & 1;
    double sAcc = 0.0, qAcc = 0.0;
    for (int tile = wh; tile < 7; tile += 2) {
        int pw = tile * 8 + pwl;
        int pwc = min(pw, 48);
        int py = pwc / 7, px = pwc - py * 7;
        int pbase = (2 * py + dy) * 16 + 2 * px + dx;
        v16f acc;
        #pragma unroll
        for (int i = 0; i < 16; ++i) acc[i] = 0.f;
        #pragma unroll
        for (int tp = 0; tp < 9; ++tp) {
            int p = pbase + (tp / 3) * 16 + (tp % 3);
            int psw = (p ^ (p >> 4)) & 3;
            #pragma unroll
            for (int kh = 0; kh < 2; ++kh) {
                int g = kh * 2 + q;
                int idx = ibase + p * 16 + ((g ^ psw) << 2);
                v8s a = *(const v8s*)&lds[idx];
                acc = __builtin_amdgcn_mfma_f32_32x32x16_bf16(a, wfr[tp * 2 + kh], acc, 0, 0, 0);
            }
        }
        #pragma unroll
        for (int g4 = 0; g4 < 4; ++g4) {
            float mx = fmaxf(fmaxf(acc[4 * g4], acc[4 * g4 + 1]),
                             fmaxf(acc[4 * g4 + 2], acc[4 * g4 + 3]));
            int pwo = tile * 8 + 2 * g4 + q;
            if (pwo < 49) {
                p1[((size_t)n * 49 + pwo) * 32 + ncol] = mx;
                double v = (double)mx;
                sAcc += v; qAcc += v * v;
            }
        }
    }
    __syncthreads();
    double* red = (double*)lds;
    red[(wv * 2 + q) * 32 + ncol] = sAcc;
    red[256 + (wv * 2 + q) * 32 + ncol] = qAcc;
    __syncthreads();
    if (t < 32) {
        double S = 0.0, Q = 0.0;
        #pragma unroll
        for (int i = 0; i < 8; ++i) { S += red[i * 32 + t]; Q += red[256 + i * 32 + t]; }
        part1[(size_t)t * 2048 + blockIdx.x] = S;
        part1[(size_t)32 * 2048 + (size_t)t * 2048 + blockIdx.x] = Q;
    }
}

// ---------------------------------------------------------------------------
// bc2m: FUSED bn1 + conv2m, 8 images/block (verbatim R5 -- the prefetch
// pipeline version; R6's wave-local variant regressed by exposing load
// latency). hp0 reconstructed inline from m via pooled max/min + sign(sc0)
// select (bit-identical). Then unchanged conv2m MFMA phase.
// ---------------------------------------------------------------------------
__global__ __launch_bounds__(256) void k_bc2m(const float* __restrict__ p1,
                                              const float* __restrict__ m,
                                              const float* __restrict__ ss,
                                              const uint16_t* __restrict__ w2f,
                                              float* __restrict__ p2,
                                              float* __restrict__ hp1,
                                              double* __restrict__ part2) {
    __shared__ uint32_t lds[8192];   // 32 KB act image, 8 x 1024 words
    __shared__ float Htmp[1568];     // one image's H (NHWC 49x32)
    int t = threadIdx.x;
    int n0 = blockIdx.x * 8;
    int lane = t & 63, wv = t >> 6;
    int q = lane >> 5, ncol = lane & 31;

    int cb = t & 7;                    // channel-quad (c0 = cb*4)
    float sc1v[4], sh1v[4], sc0v[4], sh0v[4];
    #pragma unroll
    for (int j = 0; j < 4; ++j) {
        sc1v[j] = ss[64 + cb * 4 + j]; sh1v[j] = ss[96 + cb * 4 + j];
        sc0v[j] = ss[cb * 4 + j];      sh0v[j] = ss[32 + cb * 4 + j];
    }
    // image-invariant source geometry
    int pw0 = t >> 3;                  // slot0 output pixel (0..31)
    int py0 = pw0 / 7, px0 = pw0 - py0 * 7;
    int mb0 = ((2 * py0) * 14 + 2 * px0) * 8 + cb;   // float4 index into m[196][8]
    int pw1 = 32 + (t >> 3);           // slot1 output pixel (32..48), t<136
    int py1 = pw1 / 7, px1 = pw1 - py1 * 7;
    int mb1 = ((2 * py1) * 14 + 2 * px1) * 8 + cb;

    // Prefetch image 0
    float4 pa, pb, a0, a1, a2, a3, b0_, b1_, b2_, b3_;
    {
        const float4* P4 = (const float4*)(p1 + (size_t)n0 * 1568);
        const float4* M4 = (const float4*)(m + (size_t)n0 * 6272);
        pa = P4[t];
        a0 = M4[mb0]; a1 = M4[mb0 + 8]; a2 = M4[mb0 + 112]; a3 = M4[mb0 + 120];
        if (t < 136) {
            pb = P4[256 + t];
            b0_ = M4[mb1]; b1_ = M4[mb1 + 8]; b2_ = M4[mb1 + 112]; b3_ = M4[mb1 + 120];
        }
    }

    float4* Ht4 = (float4*)Htmp;
    for (int img = 0; img < 8; ++img) {
        float4 npa, npb, na0, na1, na2, na3, nb0, nb1, nb2, nb3;
        if (img < 7) {
            const float4* P4 = (const float4*)(p1 + (size_t)(n0 + img + 1) * 1568);
            const float4* M4 = (const float4*)(m + (size_t)(n0 + img + 1) * 6272);
            npa = P4[t];
            na0 = M4[mb0]; na1 = M4[mb0 + 8]; na2 = M4[mb0 + 112]; na3 = M4[mb0 + 120];
            if (t < 136) {
                npb = P4[256 + t];
                nb0 = M4[mb1]; nb1 = M4[mb1 + 8]; nb2 = M4[mb1 + 112]; nb3 = M4[mb1 + 120];
            }
        }
        if (img) __syncthreads();   // previous pack/hp1 readers done with Htmp
        {
            float mx0 = fmaxf(fmaxf(a0.x, a1.x), fmaxf(a2.x, a3.x));
            float mx1 = fmaxf(fmaxf(a0.y, a1.y), fmaxf(a2.y, a3.y));
            float mx2 = fmaxf(fmaxf(a0.z, a1.z), fmaxf(a2.z, a3.z));
            float mx3 = fmaxf(fmaxf(a0.w, a1.w), fmaxf(a2.w, a3.w));
            float mn0 = fminf(fminf(a0.x, a1.x), fminf(a2.x, a3.x));
            float mn1 = fminf(fminf(a0.y, a1.y), fminf(a2.y, a3.y));
            float mn2 = fminf(fminf(a0.z, a1.z), fminf(a2.z, a3.z));
            float mn3 = fminf(fminf(a0.w, a1.w), fminf(a2.w, a3.w));
            float s0 = (sc0v[0] > 0.f) ? mx0 : mn0;
            float s1 = (sc0v[1] > 0.f) ? mx1 : mn1;
            float s2 = (sc0v[2] > 0.f) ? mx2 : mn2;
            float s3 = (sc0v[3] > 0.f) ? mx3 : mn3;
            float4 hv;
            hv.x = fmaf(sc1v[0], pa.x, sh1v[0]) + fmaf(sc0v[0], s0, sh0v[0]);
            hv.y = fmaf(sc1v[1], pa.y, sh1v[1]) + fmaf(sc0v[1], s1, sh0v[1]);
            hv.z = fmaf(sc1v[2], pa.z, sh1v[2]) + fmaf(sc0v[2], s2, sh0v[2]);
            hv.w = fmaf(sc1v[3], pa.w, sh1v[3]) + fmaf(sc0v[3], s3, sh0v[3]);
            Ht4[t] = hv;
            if (t < 136) {
                float ux0 = fmaxf(fmaxf(b0_.x, b1_.x), fmaxf(b2_.x, b3_.x));
                float ux1 = fmaxf(fmaxf(b0_.y, b1_.y), fmaxf(b2_.y, b3_.y));
                float ux2 = fmaxf(fmaxf(b0_.z, b1_.z), fmaxf(b2_.z, b3_.z));
                float ux3 = fmaxf(fmaxf(b0_.w, b1_.w), fmaxf(b2_.w, b3_.w));
                float un0 = fminf(fminf(b0_.x, b1_.x), fminf(b2_.x, b3_.x));
                float un1 = fminf(fminf(b0_.y, b1_.y), fminf(b2_.y, b3_.y));
                float un2 = fminf(fminf(b0_.z, b1_.z), fminf(b2_.z, b3_.z));
                float un3 = fminf(fminf(b0_.w, b1_.w), fminf(b2_.w, b3_.w));
                float u0 = (sc0v[0] > 0.f) ? ux0 : un0;
                float u1 = (sc0v[1] > 0.f) ? ux1 : un1;
                float u2 = (sc0v[2] > 0.f) ? ux2 : un2;
                float u3 = (sc0v[3] > 0.f) ? ux3 : un3;
                float4 hw;
                hw.x = fmaf(sc1v[0], pb.x, sh1v[0]) + fmaf(sc0v[0], u0, sh0v[0]);
                hw.y = fmaf(sc1v[1], pb.y, sh1v[1]) + fmaf(sc0v[1], u1, sh0v[1]);
                hw.z = fmaf(sc1v[2], pb.z, sh1v[2]) + fmaf(sc0v[2], u2, sh0v[2]);
                hw.w = fmaf(sc1v[3], pb.w, sh1v[3]) + fmaf(sc0v[3], u3, sh0v[3]);
                Ht4[256 + t] = hw;
            }
        }
        __syncthreads();
        // pack act words (identical mapping to old k_bn1 sp[i])
        uint32_t* ap = &lds[img * 1024];
        #pragma unroll
        for (int ii = 0; ii < 4; ++ii) {
            int i = t + ii * 256;
            int pp = i >> 4, r = i & 15;
            int y = pp >> 3, xq = pp & 7;
            uint32_t d = 0u;
            if (y >= 1 && xq >= 1) {
                int pix = (y - 1) * 7 + (xq - 1);
                int sub = r & 3;
                int g = (r >> 2) ^ (pp & 3);
                int c0 = ((g << 2) | sub) * 2;
                float h0 = Htmp[pix * 32 + c0];
                float h1 = Htmp[pix * 32 + c0 + 1];
                uint32_t w0b = (h0 > 0.f) ? 0x3F80u : ((h0 < 0.f) ? 0xBF80u : 0u);
                uint32_t w1b = (h1 > 0.f) ? 0x3F80u : ((h1 < 0.f) ? 0xBF80u : 0u);
                d = w0b | (w1b << 16);
            }
            ap[i] = d;
        }
        // hp1 (identical fmax tree / dest layout to old k_bn1)
        for (int jj = t; jj < 288; jj += 256) {
            int c = jj / 9, pix = jj - c * 9;
            int r = pix / 3, qq = pix - r * 3;
            float e0 = Htmp[((2 * r) * 7 + 2 * qq) * 32 + c];
            float e1 = Htmp[((2 * r) * 7 + 2 * qq + 1) * 32 + c];
            float e2 = Htmp[((2 * r + 1) * 7 + 2 * qq) * 32 + c];
            float e3 = Htmp[((2 * r + 1) * 7 + 2 * qq + 1) * 32 + c];
            hp1[(size_t)(n0 + img) * 288 + c * 9 + pix] = fmaxf(fmaxf(e0, e1), fmaxf(e2, e3));
        }
        pa = npa; pb = npb;
        a0 = na0; a1 = na1; a2 = na2; a3 = na3;
        b0_ = nb0; b1_ = nb1; b2_ = nb2; b3_ = nb3;
    }
    __syncthreads();   // all act words visible to all waves

    // weights loaded after staging (reduces concurrent VGPR pressure)
    v8s wfr[18];
    #pragma unroll
    for (int f = 0; f < 18; ++f)
        wfr[f] = *(const v8s*)(w2f + (f * 2 + q) * 256 + ncol * 8);

    // ---- conv2m MFMA phase (unchanged) ----
    int mmm = lane & 31;
    int quad = mmm & 3, pwl = mmm >> 2;
    int dy = quad >> 1, dx = quad & 1;
    double sAcc = 0.0, qAcc = 0.0;
    for (int tile = wv; tile < 9; tile += 4) {
        int pwg = tile * 8 + pwl;
        int img = pwg / 9, pwi = pwg - img * 9;
        int py = pwi / 3, px = pwi - py * 3;
        int pbase = (2 * py + dy) * 8 + 2 * px + dx;
        v16f acc;
        #pragma unroll
        for (int i = 0; i < 16; ++i) acc[i] = 0.f;
        #pragma unroll
        for (int tp = 0; tp < 9; ++tp) {
            int p = pbase + (tp / 3) * 8 + (tp % 3);
            int psw = p & 3;
            #pragma unroll
            for (int kh = 0; kh < 2; ++kh) {
                int g = kh * 2 + q;
                int idx = img * 1024 + p * 16 + ((g ^ psw) << 2);
                v8s a = *(const v8s*)&lds[idx];
                acc = __builtin_amdgcn_mfma_f32_32x32x16_bf16(a, wfr[tp * 2 + kh], acc, 0, 0, 0);
            }
        }
        #pragma unroll
        for (int g4 = 0; g4 < 4; ++g4) {
            float mx = fmaxf(fmaxf(acc[4 * g4], acc[4 * g4 + 1]),
                             fmaxf(acc[4 * g4 + 2], acc[4 * g4 + 3]));
            int pwo = tile * 8 + 2 * g4 + q;
            int oimg = pwo / 9, opwi = pwo - oimg * 9;
            p2[(size_t)(n0 + oimg) * 288 + ncol * 9 + opwi] = mx;
            double v = (double)mx;
            sAcc += v; qAcc += v * v;
        }
    }
    __syncthreads();
    double* red = (double*)lds;
    red[(wv * 2 + q) * 32 + ncol] = sAcc;
    red[256 + (wv * 2 + q) * 32 + ncol] = qAcc;
    __syncthreads();
    if (t < 32) {
        double S = 0.0, Q = 0.0;
        #pragma unroll
        for (int i = 0; i < 8; ++i) { S += red[i * 32 + t]; Q += red[256 + i * 32 + t]; }
        part2[(size_t)t * 512 + blockIdx.x] = S;
        part2[(size_t)32 * 512 + (size_t)t * 512 + blockIdx.x] = Q;
    }
}

// ---------------------------------------------------------------------------
// FC: out[n,k] = sum_j (bn2(p2)+hp1)[n,j] * fw[k,j] + fb[k].  Wave per image.
// ---------------------------------------------------------------------------
__global__ __launch_bounds__(256) void k_fc(const float* __restrict__ p2,
                                            const float* __restrict__ hp1,
                                            const float* __restrict__ ss,
                                            const float* __restrict__ fw,
                                            const float* __restrict__ fb,
                                            float* __restrict__ outv) {
    int wv = threadIdx.x >> 6, l = threadIdx.x & 63;
    int n = blockIdx.x * 4 + wv;
    float acc[10];
    #pragma unroll
    for (int k = 0; k < 10; ++k) acc[k] = 0.f;
    #pragma unroll
    for (int i = 0; i < 5; ++i) {
        int j = l + 64 * i;
        if (j < 288) {
            int c = j / 9;
            float h = fmaf(ss[128 + c], p2[n * 288 + j], ss[160 + c]) + hp1[n * 288 + j];
            #pragma unroll
            for (int k = 0; k < 10; ++k)
                acc[k] = fmaf(h, fw[k * 288 + j], acc[k]);
        }
    }
    #pragma unroll
    for (int k = 0; k < 10; ++k) {
        float s = acc[k];
        #pragma unroll
        for (int o = 32; o > 0; o >>= 1) s += __shfl_down(s, o);
        if (l == 0) outv[n * 10 + k] = s + fb[k];
    }
}

// ---------------------------------------------------------------------------
// Workspace layout (bytes) -- FULLY DISJOINT, no overlays, peak 141.3 MB:
//   ss    @1024      (768 B)
//   w1f   @2048      (18,432)       ends 20,480
//   w2f   @20480     (18,432)       ends 38,912
//   part1 @38912     (1,048,576)    ends 1,087,488
//   part0 @1087488   (2,097,152)    ends 3,184,640
//   p1    @3184640   (25,690,112)   ends 28,874,752
//   p2    @28874752  (4,718,592)    ends 33,593,344
//   hp1   @33593344  (4,718,592)    ends 38,311,936
//   part2 @38311936  (262,144)      ends 38,574,080
//   m     @38574080  (102,760,448)  ends 141,334,528
// 7 kernel nodes. Kernel-boundary ordering is the only cross-block sync.
// ---------------------------------------------------------------------------
extern "C" void kernel_launch(void* const* d_in, const int* in_sizes, int n_in,
                              void* d_out, int out_size, void* d_ws, size_t ws_size,
                              hipStream_t stream) {
    (void)in_sizes; (void)n_in; (void)out_size; (void)ws_size;
    const float* x  = (const float*)d_in[0];
    const float* w0 = (const float*)d_in[1];
    const float* g0 = (const float*)d_in[2];
    const float* b0 = (const float*)d_in[3];
    const float* w1 = (const float*)d_in[4];
    const float* g1 = (const float*)d_in[5];
    const float* b1 = (const float*)d_in[6];
    const float* w2 = (const float*)d_in[7];
    const float* g2 = (const float*)d_in[8];
    const float* b2 = (const float*)d_in[9];
    const float* fw = (const float*)d_in[10];
    const float* fb = (const float*)d_in[11];
    float* outv = (float*)d_out;
    char* ws = (char*)d_ws;

    float*     ss    = (float*)(ws + 1024);
    uint16_t*  w1f   = (uint16_t*)(ws + 2048);
    uint16_t*  w2f   = (uint16_t*)(ws + 20480);
    double*    part1 = (double*)(ws + 38912);
    double*    part0 = (double*)(ws + 1087488);
    float*     p1    = (float*)(ws + 3184640);
    float*     p2    = (float*)(ws + 28874752);
    float*     hp1   = (float*)(ws + 33593344);
    double*    part2 = (double*)(ws + 38311936);
    float*     m     = (float*)(ws + 38574080);

    k_conv0f2<<<BATCH / 2, 448, 0, stream>>>(x, w0, w1, w2, w1f, w2f, part0, m);
    k_finalize<<<32, 256, 0, stream>>>(part0, 4096, g0, b0, 1.0 / (BATCH * 196.0), ss);

    k_conv1s<<<BATCH / 2, 256, 0, stream>>>(m, ss, w1f, p1, part1);
    k_finalize<<<32, 256, 0, stream>>>(part1, 2048, g1, b1, 1.0 / (BATCH * 49.0), ss + 64);

    k_bc2m<<<BATCH / 8, 256, 0, stream>>>(p1, m, ss, w2f, p2, hp1, part2);
    k_finalize<<<32, 256, 0, stream>>>(part2, 512, g2, b2, 1.0 / (BATCH * 9.0), ss + 128);

    k_fc<<<BATCH / 4, 256, 0, stream>>>(p2, hp1, ss, fw, fb, outv);
}